// Round 16
// baseline (1040.323 us; speedup 1.0000x reference)
//
#include <hip/hip_runtime.h>
#include <stdint.h>

#define HW 16384
#define CH 512
#define KR 19

typedef float f32x4 __attribute__((ext_vector_type(4)));
typedef _Float16 half8 __attribute__((ext_vector_type(8)));
typedef unsigned short us8 __attribute__((ext_vector_type(8)));

__device__ __forceinline__ unsigned short f2h(float f) {
    union { _Float16 h; unsigned short u; } v; v.h = (_Float16)f; return v.u;
}

__global__ void ObjectAttentionBlock_1176821039805_kernel() {}

// ---------------- prep: weights fp32->fp16, fused BN constants ----------------
__global__ __launch_bounds__(256) void prep_kernel(
    const float* __restrict__ wp1, const float* __restrict__ wp2, const float* __restrict__ wu,
    unsigned short* __restrict__ wp1h, unsigned short* __restrict__ wp2h, unsigned short* __restrict__ wuh,
    const float* gp1, const float* bp1, const float* mp1, const float* vp1,
    const float* gp2, const float* bp2, const float* mp2, const float* vp2,
    const float* gu,  const float* bu,  const float* mu,  const float* vu,
    float* __restrict__ cons)
{
    int i = blockIdx.x * 256 + threadIdx.x;
    if (i < CH * CH) {
        wp1h[i] = f2h(wp1[i]);
        wp2h[i] = f2h(wp2[i]);
        wuh[i]  = f2h(wu[i]);
    }
    if (i < CH) {
        float s1 = gp1[i] * rsqrtf(vp1[i] + 1e-5f);
        cons[i] = s1;          cons[512 + i]  = bp1[i] - mp1[i] * s1;
        float s2 = gp2[i] * rsqrtf(vp2[i] + 1e-5f);
        cons[1024 + i] = s2;   cons[1536 + i] = bp2[i] - mp2[i] * s2;
        float su = gu[i] * rsqrtf(vu[i] + 1e-5f);
        cons[2048 + i] = su;   cons[2560 + i] = bu[i] - mu[i] * su;
    }
}

// ---------------- x [n][c][hw] fp32 -> xT [n][hw][c] fp16 ----------------
__global__ __launch_bounds__(256) void transpose_kernel(
    const float* __restrict__ x, unsigned short* __restrict__ xT)
{
    __shared__ unsigned short t[64][66];
    const int n  = blockIdx.z;
    const int c0 = blockIdx.y * 64;
    const int m0 = blockIdx.x * 64;
    const int tx = threadIdx.x & 63;
    const int ty = threadIdx.x >> 6;
    const float* xb = x + ((size_t)n * CH + c0) * HW + m0;
    #pragma unroll
    for (int r = 0; r < 16; ++r) {
        int cl = ty * 16 + r;
        t[cl][tx] = f2h(xb[(size_t)cl * HW + tx]);
    }
    __syncthreads();
    unsigned short* xo = xT + ((size_t)n * HW + m0) * CH + c0;
    #pragma unroll
    for (int r = 0; r < 16; ++r) {
        int ml = ty * 16 + r;
        xo[(size_t)ml * CH + tx] = t[tx][ml];
    }
}

// ---------------- proxy-side tiny GEMMs (fp32 vector math) ----------------
__global__ __launch_bounds__(256) void kv1_kernel(
    const float* __restrict__ proxy, const float* __restrict__ wo1, const float* __restrict__ wd,
    const float* go1, const float* bo1, const float* mo1, const float* vo1,
    const float* gd,  const float* bd,  const float* md,  const float* vd,
    float* __restrict__ t1, float* __restrict__ vout)
{
    const int n  = blockIdx.x;
    const int o0 = blockIdx.y * 64;
    const float* px = proxy + (size_t)n * CH * KR;
    for (int idx = threadIdx.x; idx < 64 * KR; idx += 256) {
        int o = o0 + idx / KR;
        int j = idx % KR;
        float a1 = 0.f, a2 = 0.f;
        for (int c = 0; c < CH; ++c) {
            float p = px[c * KR + j];
            a1 += wo1[o * CH + c] * p;
            a2 += wd [o * CH + c] * p;
        }
        float s1 = go1[o] * rsqrtf(vo1[o] + 1e-5f);
        float s2 = gd[o]  * rsqrtf(vd[o]  + 1e-5f);
        t1  [((size_t)n * CH + o) * KR + j] = fmaxf(a1 * s1 + (bo1[o] - mo1[o] * s1), 0.f);
        vout[((size_t)n * CH + o) * KR + j] = fmaxf(a2 * s2 + (bd[o]  - md[o]  * s2), 0.f);
    }
}

__global__ __launch_bounds__(256) void kv2_kernel(
    const float* __restrict__ t1, const float* __restrict__ wo2,
    const float* go2, const float* bo2, const float* mo2, const float* vo2,
    float* __restrict__ kout)
{
    const int n  = blockIdx.x;
    const int o0 = blockIdx.y * 64;
    const float* tb = t1 + (size_t)n * CH * KR;
    for (int idx = threadIdx.x; idx < 64 * KR; idx += 256) {
        int o = o0 + idx / KR;
        int j = idx % KR;
        float a = 0.f;
        for (int c = 0; c < CH; ++c) a += wo2[o * CH + c] * tb[c * KR + j];
        float s = go2[o] * rsqrtf(vo2[o] + 1e-5f);
        kout[((size_t)n * CH + o) * KR + j] = fmaxf(a * s + (bo2[o] - mo2[o] * s), 0.f);
    }
}

// ---------------- compact pad: KT [8][32][512], VT [8][512][32] (fp16, zero-padded) ----------------
__global__ __launch_bounds__(256) void pad32_kernel(
    const float* __restrict__ kbuf, const float* __restrict__ vbuf,
    unsigned short* __restrict__ kt32, unsigned short* __restrict__ vt32)
{
    int idx = blockIdx.x * 256 + threadIdx.x;      // < 131072
    {   // KT[n][j][c] = k[n][c][j]
        int n = idx >> 14, rem = idx & 16383;
        int j = rem >> 9, c = rem & 511;
        kt32[idx] = (j < KR) ? f2h(kbuf[((size_t)(n * CH + c)) * KR + j]) : (unsigned short)0;
    }
    {   // VT[n][c][j] = v[n][c][j]
        int n = idx >> 14, rem = idx & 16383;
        int c = rem >> 5, j = rem & 31;
        vt32[idx] = (j < KR) ? f2h(vbuf[((size_t)(n * CH + c)) * KR + j]) : (unsigned short)0;
    }
}

// ---------------- MEGA kernel: per 64-row tile: GEMM1 -> GEMM2 -> attn -> GEMM3 ----------------
// Tiles live in LDS (swizzled [64][512] fp16: elem [r][k] at r*512 + ((k>>3 ^ (r&7))<<3) + (k&7)).
// W streamed per 128-col sub-tile in [128][64] k-slices (round-5-verified staging/read math).
// All sync via __syncthreads (no counted vmcnt) -> race-free by construction.
__global__ __launch_bounds__(256) void mega_kernel(
    const unsigned short* __restrict__ xT,    // [131072][512] fp16 k-contig
    const unsigned short* __restrict__ w1,
    const unsigned short* __restrict__ w2,
    const unsigned short* __restrict__ wu,
    const float* __restrict__ cons,
    const unsigned short* __restrict__ kt32,  // [8][32][512]
    const unsigned short* __restrict__ vt32,  // [8][512][32]
    float* __restrict__ outp)                 // [8][512][16384] fp32
{
    __shared__ __align__(16) char lds[147456];
    unsigned short* T1 = (unsigned short*)lds;             // 64KB: xT -> (q2 -> ctx in place)
    unsigned short* T2 = (unsigned short*)(lds + 65536);   // 64KB: q1; then KT|VT; then fp32 epi
    unsigned short* WS = (unsigned short*)(lds + 131072);  // 16KB: W k-slice [128][64]; att_l in attn

    const int tid  = threadIdx.x;
    const int lane = tid & 63;
    const int wave = tid >> 6;
    const int rl   = lane & 15;
    const int kch  = lane >> 4;
    const int Rw   = wave * 16;
    const int R0   = blockIdx.x * 64;
    const int n    = R0 >> 14;
    const int m0   = R0 & (HW - 1);

    // ---- stage xT tile -> T1 ----
    #pragma unroll
    for (int q = 0; q < 16; ++q) {
        int g = q * 256 + tid;              // 4096 chunks of 8 shorts
        int r = g >> 6, kc = g & 63;
        us8 v = *(const us8*)(xT + (size_t)(R0 + r) * 512 + kc * 8);
        *(us8*)(T1 + r * 512 + ((kc ^ (r & 7)) << 3)) = v;
    }
    __syncthreads();

    // ---- generic GEMM phase: out[64][512] = BN_ReLU(in[64][512] x W^T) ----
    auto gemm_phase = [&](const unsigned short* inT, unsigned short* outT,
                          const unsigned short* Wp, const float* scp, const float* shp,
                          int fin) {
        for (int jsub = 0; jsub < 4; ++jsub) {
            us8 wreg[4];
            size_t gW[4]; int lW[4];
            #pragma unroll
            for (int q = 0; q < 4; ++q) {
                int ca = q * 256 + tid;
                int r = ca >> 3, p = ca & 7;
                gW[q] = (size_t)(jsub * 128 + r) * 512 + p * 8;
                lW[q] = r * 64 + ((p ^ (r & 7)) << 3);
                wreg[q] = *(const us8*)(Wp + gW[q]);
            }
            f32x4 acc[8];
            #pragma unroll
            for (int c = 0; c < 8; ++c) acc[c] = (f32x4){0.f, 0.f, 0.f, 0.f};

            for (int ks = 0; ks < 8; ++ks) {
                __syncthreads();
                #pragma unroll
                for (int q = 0; q < 4; ++q) *(us8*)(WS + lW[q]) = wreg[q];
                __syncthreads();
                if (ks < 7) {
                    #pragma unroll
                    for (int q = 0; q < 4; ++q)
                        wreg[q] = *(const us8*)(Wp + gW[q] + (ks + 1) * 64);
                }
                #pragma unroll
                for (int s = 0; s < 2; ++s) {
                    int ck = ks * 8 + s * 4 + kch;
                    int Ra = Rw + rl;
                    half8 af = *(const half8*)(inT + Ra * 512 + ((ck ^ (Ra & 7)) << 3));
                    #pragma unroll
                    for (int cf = 0; cf < 8; ++cf) {
                        int rb = cf * 16 + rl;
                        half8 bw = *(const half8*)(WS + rb * 64 + (((s * 4 + kch) ^ (rb & 7)) << 3));
                        acc[cf] = __builtin_amdgcn_mfma_f32_16x16x32_f16(af, bw, acc[cf], 0, 0, 0);
                    }
                }
            }
            if (fin == 0) {
                #pragma unroll
                for (int cf = 0; cf < 8; ++cf) {
                    int col = jsub * 128 + cf * 16 + rl;
                    float s = scp[col], h = shp[col];
                    #pragma unroll
                    for (int e = 0; e < 4; ++e) {
                        int row = Rw + kch * 4 + e;
                        float vv = fmaxf(acc[cf][e] * s + h, 0.f);
                        outT[row * 512 + (((col >> 3) ^ (row & 7)) << 3) + (col & 7)] = f2h(vv);
                    }
                }
            } else {
                float (*epi)[66] = (float (*)[66])T2;      // [128 o][66 m] fp32, 33792 B
                __syncthreads();
                #pragma unroll
                for (int cf = 0; cf < 8; ++cf) {
                    int ol = cf * 16 + rl;
                    float s = scp[jsub * 128 + ol], h = shp[jsub * 128 + ol];
                    #pragma unroll
                    for (int e = 0; e < 4; ++e) {
                        int ml = Rw + kch * 4 + e;
                        epi[ol][ml] = fmaxf(acc[cf][e] * s + h, 0.f);
                    }
                }
                __syncthreads();
                int ol = tid >> 1, hf = tid & 1;
                size_t base = ((size_t)(n * 512 + jsub * 128 + ol) << 14) + m0 + hf * 32;
                #pragma unroll
                for (int u = 0; u < 8; ++u) {
                    f32x4 v = *(const f32x4*)&epi[ol][hf * 32 + u * 4];
                    *(f32x4*)&outp[base + u * 4] = v;
                }
            }
        }
    };

    // phase A: q1 = BN1-ReLU(xT x W1^T): T1 -> T2
    gemm_phase(T1, T2, w1, cons, cons + 512, 0);
    // phase B: q2 = BN2-ReLU(q1 x W2^T): T2 -> T1
    gemm_phase(T2, T1, w2, cons + 1024, cons + 1536, 0);

    // ---- phase C: attention (q2 in T1 -> ctx in T1, per-wave rows) ----
    __syncthreads();                                   // all phase-B T2 reads done
    #pragma unroll
    for (int q = 0; q < 8; ++q) {                      // KT [32][512] -> T2 swizzled
        int g = q * 256 + tid;
        int r = g >> 6, kc = g & 63;
        us8 v = *(const us8*)(kt32 + (size_t)n * 16384 + r * 512 + kc * 8);
        *(us8*)(T2 + r * 512 + ((kc ^ (r & 7)) << 3)) = v;
    }
    #pragma unroll
    for (int q = 0; q < 8; ++q) {                      // VT [512][32] -> T2+16384 swizzled
        int g = q * 256 + tid;
        int c = g >> 2, jc = g & 3;
        us8 v = *(const us8*)(vt32 + (size_t)n * 16384 + c * 32 + jc * 8);
        *(us8*)(T2 + 16384 + c * 32 + ((jc ^ (c & 3)) << 3)) = v;
    }
    __syncthreads();

    f32x4 accS[2];
    accS[0] = (f32x4){0.f, 0.f, 0.f, 0.f};
    accS[1] = (f32x4){0.f, 0.f, 0.f, 0.f};
    for (int it = 0; it < 16; ++it) {
        int ck = it * 4 + kch;
        int Ra = Rw + rl;
        half8 aq = *(const half8*)(T1 + Ra * 512 + ((ck ^ (Ra & 7)) << 3));
        #pragma unroll
        for (int t = 0; t < 2; ++t) {
            int jf = t * 16 + rl;
            half8 bk = *(const half8*)(T2 + jf * 512 + ((ck ^ (jf & 7)) << 3));
            accS[t] = __builtin_amdgcn_mfma_f32_16x16x32_f16(aq, bk, accS[t], 0, 0, 0);
        }
    }
    const float scale = 0.044194173824159216f;         // 512^-0.5
    const bool v1 = rl < 3;
    unsigned short* att_l = WS;                        // [64][40] fp16, 5120 B
    #pragma unroll
    for (int e = 0; e < 4; ++e) {
        float s0  = accS[0][e] * scale;
        float s1v = accS[1][e] * scale;
        float m = v1 ? fmaxf(s0, s1v) : s0;
        m = fmaxf(m, __shfl_xor(m, 1));
        m = fmaxf(m, __shfl_xor(m, 2));
        m = fmaxf(m, __shfl_xor(m, 4));
        m = fmaxf(m, __shfl_xor(m, 8));
        float a0 = __expf(s0 - m);
        float a1 = v1 ? __expf(s1v - m) : 0.f;
        float sm = a0 + a1;
        sm += __shfl_xor(sm, 1);
        sm += __shfl_xor(sm, 2);
        sm += __shfl_xor(sm, 4);
        sm += __shfl_xor(sm, 8);
        float inv = 1.0f / sm;
        int R2 = Rw + kch * 4 + e;
        att_l[R2 * 40 + rl]      = f2h(a0 * inv);
        att_l[R2 * 40 + 16 + rl] = f2h(a1 * inv);
    }
    __syncthreads();                                   // cross-lane att_l visibility
    half8 a2 = *(const half8*)(att_l + (Rw + rl) * 40 + kch * 8);
    for (int jsub = 0; jsub < 4; ++jsub) {
        #pragma unroll
        for (int cf = 0; cf < 8; ++cf) {
            int c = jsub * 128 + cf * 16 + rl;
            half8 bv = *(const half8*)(T2 + 16384 + c * 32 + ((kch ^ (c & 3)) << 3));
            f32x4 o = __builtin_amdgcn_mfma_f32_16x16x32_f16(
                a2, bv, (f32x4){0.f, 0.f, 0.f, 0.f}, 0, 0, 0);
            #pragma unroll
            for (int e = 0; e < 4; ++e) {
                int row = Rw + kch * 4 + e;
                T1[row * 512 + (((c >> 3) ^ (row & 7)) << 3) + (c & 7)] = f2h(o[e]);
            }
        }
    }
    __syncthreads();                                   // ctx complete before phase D

    // phase D: out = BNu-ReLU(ctx x Wu^T) -> fp32 NCHW
    gemm_phase(T1, (unsigned short*)0, wu, cons + 2048, cons + 2560, 1);
}

extern "C" void kernel_launch(void* const* d_in, const int* in_sizes, int n_in,
                              void* d_out, int out_size, void* d_ws, size_t ws_size,
                              hipStream_t stream)
{
    const float* x     = (const float*)d_in[0];
    const float* proxy = (const float*)d_in[1];
    const float* wp1   = (const float*)d_in[2];
    const float* wp2   = (const float*)d_in[3];
    const float* wo1   = (const float*)d_in[4];
    const float* wo2   = (const float*)d_in[5];
    const float* wd    = (const float*)d_in[6];
    const float* wu    = (const float*)d_in[7];
    const float* gp1 = (const float*)d_in[8],  *bp1 = (const float*)d_in[9];
    const float* mp1 = (const float*)d_in[10], *vp1 = (const float*)d_in[11];
    const float* gp2 = (const float*)d_in[12], *bp2 = (const float*)d_in[13];
    const float* mp2 = (const float*)d_in[14], *vp2 = (const float*)d_in[15];
    const float* go1 = (const float*)d_in[16], *bo1 = (const float*)d_in[17];
    const float* mo1 = (const float*)d_in[18], *vo1 = (const float*)d_in[19];
    const float* go2 = (const float*)d_in[20], *bo2 = (const float*)d_in[21];
    const float* mo2 = (const float*)d_in[22], *vo2 = (const float*)d_in[23];
    const float* gd  = (const float*)d_in[24], *bd  = (const float*)d_in[25];
    const float* md  = (const float*)d_in[26], *vd  = (const float*)d_in[27];
    const float* gu  = (const float*)d_in[28], *bu  = (const float*)d_in[29];
    const float* mu  = (const float*)d_in[30], *vu  = (const float*)d_in[31];

    char* ws = (char*)d_ws;
    unsigned short* r0   = (unsigned short*)ws;               // 134 MB: xT fp16
    unsigned short* wp1h = (unsigned short*)(ws + 134217728);
    unsigned short* wp2h = wp1h + 262144;
    unsigned short* wuh  = wp2h + 262144;
    float* t1   = (float*)(wuh + 262144);
    float* kbuf = t1 + 8 * CH * KR;
    float* vbuf = kbuf + 8 * CH * KR;
    float* cons = vbuf + 8 * CH * KR;                         // 3072 floats
    unsigned short* kt32 = (unsigned short*)(cons + 3072);    // [8][32][512]
    unsigned short* vt32 = kt32 + 131072;                     // [8][512][32]
    float* outf = (float*)d_out;

    prep_kernel<<<1024, 256, 0, stream>>>(wp1, wp2, wu, wp1h, wp2h, wuh,
        gp1, bp1, mp1, vp1, gp2, bp2, mp2, vp2, gu, bu, mu, vu, cons);
    transpose_kernel<<<dim3(256, 8, 8), 256, 0, stream>>>(x, r0);
    kv1_kernel<<<dim3(8, 8), 256, 0, stream>>>(proxy, wo1, wd,
        go1, bo1, mo1, vo1, gd, bd, md, vd, t1, vbuf);
    kv2_kernel<<<dim3(8, 8), 256, 0, stream>>>(t1, wo2, go2, bo2, mo2, vo2, kbuf);
    pad32_kernel<<<512, 256, 0, stream>>>(kbuf, vbuf, kt32, vt32);

    // fused GEMM1 + GEMM2 + attention + GEMM3, one pass over the image
    mega_kernel<<<2048, 256, 0, stream>>>(r0, wp1h, wp2h, wuh, cons, kt32, vt32, outf);
}

// Round 17
// 709.605 us; speedup vs baseline: 1.4661x; 1.4661x over previous
//
#include <hip/hip_runtime.h>
#include <stdint.h>

#define HW 16384
#define CH 512
#define KR 19

typedef float f32x4 __attribute__((ext_vector_type(4)));
typedef _Float16 half8 __attribute__((ext_vector_type(8)));
typedef unsigned short us8 __attribute__((ext_vector_type(8)));
typedef unsigned short us4 __attribute__((ext_vector_type(4)));

__device__ __forceinline__ unsigned short f2h(float f) {
    union { _Float16 h; unsigned short u; } v; v.h = (_Float16)f; return v.u;
}

__global__ void ObjectAttentionBlock_1176821039805_kernel() {}

// ---------------- prep: weights fp32->fp16, fused BN constants ----------------
__global__ __launch_bounds__(256) void prep_kernel(
    const float* __restrict__ wp1, const float* __restrict__ wp2, const float* __restrict__ wu,
    unsigned short* __restrict__ wp1h, unsigned short* __restrict__ wp2h, unsigned short* __restrict__ wuh,
    const float* gp1, const float* bp1, const float* mp1, const float* vp1,
    const float* gp2, const float* bp2, const float* mp2, const float* vp2,
    const float* gu,  const float* bu,  const float* mu,  const float* vu,
    float* __restrict__ cons)
{
    int i = blockIdx.x * 256 + threadIdx.x;
    if (i < CH * CH) {
        wp1h[i] = f2h(wp1[i]);
        wp2h[i] = f2h(wp2[i]);
        wuh[i]  = f2h(wu[i]);
    }
    if (i < CH) {
        float s1 = gp1[i] * rsqrtf(vp1[i] + 1e-5f);
        cons[i] = s1;          cons[512 + i]  = bp1[i] - mp1[i] * s1;
        float s2 = gp2[i] * rsqrtf(vp2[i] + 1e-5f);
        cons[1024 + i] = s2;   cons[1536 + i] = bp2[i] - mp2[i] * s2;
        float su = gu[i] * rsqrtf(vu[i] + 1e-5f);
        cons[2048 + i] = su;   cons[2560 + i] = bu[i] - mu[i] * su;
    }
}

// ---------------- x [n][c][hw] fp32 -> xT [n][hw][c] fp16 (vectorized) ----------------
// 64ch x 128px tile; f32x4 loads; us8 stores (8 lanes = 128B contiguous per row).
__global__ __launch_bounds__(256) void transpose_kernel(
    const float* __restrict__ x, unsigned short* __restrict__ xT)
{
    __shared__ unsigned short t[64][140];   // pad 140: <=4-way on column reads, 8B-aligned rows
    const int n  = blockIdx.z;
    const int c0 = blockIdx.y * 64;
    const int m0 = blockIdx.x * 128;
    const int tid = threadIdx.x;
    const int cl  = tid >> 5;               // 0..7
    const int ml  = (tid & 31) * 4;
    #pragma unroll
    for (int q = 0; q < 8; ++q) {
        int c = cl + q * 8;
        f32x4 v = *(const f32x4*)(x + (((size_t)(n * CH + c0 + c)) << 14) + m0 + ml);
        us4 h = {f2h(v[0]), f2h(v[1]), f2h(v[2]), f2h(v[3])};
        *(us4*)&t[c][ml] = h;
    }
    __syncthreads();
    #pragma unroll
    for (int q = 0; q < 4; ++q) {
        int idx = q * 256 + tid;            // 1024 us8 chunks
        int m = idx >> 3, cc = idx & 7;
        us8 v;
        #pragma unroll
        for (int e = 0; e < 8; ++e) v[e] = t[cc * 8 + e][m];
        *(us8*)(xT + ((size_t)(n * HW + m0 + m)) * 512 + c0 + cc * 8) = v;
    }
}

// ---------------- proxy-side tiny GEMMs (fp32 vector math) ----------------
__global__ __launch_bounds__(256) void kv1_kernel(
    const float* __restrict__ proxy, const float* __restrict__ wo1, const float* __restrict__ wd,
    const float* go1, const float* bo1, const float* mo1, const float* vo1,
    const float* gd,  const float* bd,  const float* md,  const float* vd,
    float* __restrict__ t1, float* __restrict__ vout)
{
    const int n  = blockIdx.x;
    const int o0 = blockIdx.y * 64;
    const float* px = proxy + (size_t)n * CH * KR;
    for (int idx = threadIdx.x; idx < 64 * KR; idx += 256) {
        int o = o0 + idx / KR;
        int j = idx % KR;
        float a1 = 0.f, a2 = 0.f;
        for (int c = 0; c < CH; ++c) {
            float p = px[c * KR + j];
            a1 += wo1[o * CH + c] * p;
            a2 += wd [o * CH + c] * p;
        }
        float s1 = go1[o] * rsqrtf(vo1[o] + 1e-5f);
        float s2 = gd[o]  * rsqrtf(vd[o]  + 1e-5f);
        t1  [((size_t)n * CH + o) * KR + j] = fmaxf(a1 * s1 + (bo1[o] - mo1[o] * s1), 0.f);
        vout[((size_t)n * CH + o) * KR + j] = fmaxf(a2 * s2 + (bd[o]  - md[o]  * s2), 0.f);
    }
}

__global__ __launch_bounds__(256) void kv2_kernel(
    const float* __restrict__ t1, const float* __restrict__ wo2,
    const float* go2, const float* bo2, const float* mo2, const float* vo2,
    float* __restrict__ kout)
{
    const int n  = blockIdx.x;
    const int o0 = blockIdx.y * 64;
    const float* tb = t1 + (size_t)n * CH * KR;
    for (int idx = threadIdx.x; idx < 64 * KR; idx += 256) {
        int o = o0 + idx / KR;
        int j = idx % KR;
        float a = 0.f;
        for (int c = 0; c < CH; ++c) a += wo2[o * CH + c] * tb[c * KR + j];
        float s = go2[o] * rsqrtf(vo2[o] + 1e-5f);
        kout[((size_t)n * CH + o) * KR + j] = fmaxf(a * s + (bo2[o] - mo2[o] * s), 0.f);
    }
}

// ---------------- pad K^T/V^T to fp16 MFMA operands ----------------
// KT[n][j][c] (j<19 else 0), [8][128][512];  VT[n][c][j] (j<19 else 0), [8][512][128]
__global__ __launch_bounds__(256) void pad_kernel(
    const float* __restrict__ kbuf, const float* __restrict__ vbuf,
    unsigned short* __restrict__ kt, unsigned short* __restrict__ vt)
{
    int idx = blockIdx.x * 256 + threadIdx.x;      // < 524288
    int n = idx >> 16, rem = idx & 65535;
    int j = rem >> 9, c = rem & 511;
    kt[idx] = (j < KR) ? f2h(kbuf[((size_t)(n * CH + c)) * KR + j]) : (unsigned short)0;
    int c2 = rem >> 7, j2 = rem & 127;
    vt[idx] = (j2 < KR) ? f2h(vbuf[((size_t)(n * CH + c2)) * KR + j2]) : (unsigned short)0;
}

// ---------------- NT GEMM (f16 MFMA, 2-deep reg prefetch, XCD-chunked swizzle) ----------------
#define MFMA_BODY \
        _Pragma("unroll") \
        for (int s = 0; s < 2; ++s) { \
            half8 af[4], bw[4]; \
            _Pragma("unroll") \
            for (int t = 0; t < 4; ++t) { \
                int ra = arow + t * 16; \
                af[t] = *(const half8*)(stage + ra * 64 + (((s * 4 + kch) ^ (ra & 7)) << 3)); \
                int rb = brow + t * 16; \
                bw[t] = *(const half8*)(stage + 8192 + rb * 64 + (((s * 4 + kch) ^ (rb & 7)) << 3)); \
            } \
            _Pragma("unroll") \
            for (int i = 0; i < 4; ++i) \
                _Pragma("unroll") \
                for (int j = 0; j < 4; ++j) \
                    acc[i][j] = __builtin_amdgcn_mfma_f32_16x16x32_f16(af[i], bw[j], acc[i][j], 0, 0, 0); \
        }

template<int MODE, int BN>
__global__ __launch_bounds__(256) void gemm_nt(
    const unsigned short* __restrict__ A,
    const unsigned short* __restrict__ W,
    const float* __restrict__ sc, const float* __restrict__ sh,
    void* __restrict__ outp)
{
    __shared__ __align__(16) char lds_raw[64 * 132 * 4];   // 33792 B
    unsigned short* stage = (unsigned short*)lds_raw;
    float (*epi)[132] = (float (*)[132])lds_raw;

    const int tid  = threadIdx.x;
    const int lane = tid & 63;
    const int wm = (tid >> 7) & 1;
    const int wn = (tid >> 6) & 1;
    const int id  = blockIdx.x;
    const int swz = (id & 7) * 512 + (id >> 3);            // bijective (4096 % 8 == 0)
    const int i0 = (swz >> 2) << 7;
    const int j0 = (swz & 3) << 7;

    size_t gA[4], gW[4];
    int ldso[4];
    #pragma unroll
    for (int q = 0; q < 4; ++q) {
        int ca = q * 256 + tid;
        int r = ca >> 3, p = ca & 7;
        gA[q] = (size_t)(i0 + r) * 512 + p * 8;
        gW[q] = (size_t)(j0 + r) * 512 + p * 8;
        ldso[q] = r * 64 + ((p ^ (r & 7)) << 3);
    }

    us8 vaA[4], vbA[4], vaB[4], vbB[4];
    #pragma unroll
    for (int q = 0; q < 4; ++q) {
        vaA[q] = *(const us8*)(A + gA[q]);
        vbA[q] = *(const us8*)(W + gW[q]);
        vaB[q] = *(const us8*)(A + gA[q] + 64);
        vbB[q] = *(const us8*)(W + gW[q] + 64);
    }

    f32x4 acc[4][4];
    #pragma unroll
    for (int i = 0; i < 4; ++i)
        #pragma unroll
        for (int j = 0; j < 4; ++j) acc[i][j] = (f32x4){0.f, 0.f, 0.f, 0.f};

    const int arow = wm * 64 + (lane & 15);
    const int brow = wn * 64 + (lane & 15);
    const int kch  = lane >> 4;

    #pragma unroll
    for (int kk = 0; kk < 8; kk += 2) {
        __syncthreads();
        #pragma unroll
        for (int q = 0; q < 4; ++q) {
            *(us8*)(stage + ldso[q]) = vaA[q];
            *(us8*)(stage + 8192 + ldso[q]) = vbA[q];
        }
        __syncthreads();
        if (kk < 6) {
            #pragma unroll
            for (int q = 0; q < 4; ++q) {
                vaA[q] = *(const us8*)(A + gA[q] + (kk + 2) * 64);
                vbA[q] = *(const us8*)(W + gW[q] + (kk + 2) * 64);
            }
        }
        MFMA_BODY
        __syncthreads();
        #pragma unroll
        for (int q = 0; q < 4; ++q) {
            *(us8*)(stage + ldso[q]) = vaB[q];
            *(us8*)(stage + 8192 + ldso[q]) = vbB[q];
        }
        __syncthreads();
        if (kk < 5) {
            #pragma unroll
            for (int q = 0; q < 4; ++q) {
                vaB[q] = *(const us8*)(A + gA[q] + (kk + 3) * 64);
                vbB[q] = *(const us8*)(W + gW[q] + (kk + 3) * 64);
            }
        }
        MFMA_BODY
    }

    float scv[4], shv[4];
    #pragma unroll
    for (int j = 0; j < 4; ++j) {
        int gj = j0 + wn * 64 + j * 16 + (lane & 15);
        scv[j] = BN ? sc[gj] : 1.0f;
        shv[j] = BN ? sh[gj] : 0.0f;
    }

    if (MODE == 0) {
        unsigned short* op = (unsigned short*)outp;
        #pragma unroll
        for (int i = 0; i < 4; ++i) {
            int gi = i0 + wm * 64 + i * 16 + (lane >> 4) * 4;
            #pragma unroll
            for (int j = 0; j < 4; ++j) {
                int gj = j0 + wn * 64 + j * 16 + (lane & 15);
                #pragma unroll
                for (int r = 0; r < 4; ++r) {
                    float vv = acc[i][j][r];
                    if (BN) vv = fmaxf(vv * scv[j] + shv[j], 0.f);
                    op[(size_t)(gi + r) * 512 + gj] = f2h(vv);
                }
            }
        }
    } else {
        float* op = (float*)outp;
        const int n  = i0 >> 14;
        const int mb = i0 & (HW - 1);
        #pragma unroll
        for (int h = 0; h < 2; ++h) {
            __syncthreads();
            if (wn == h) {
                #pragma unroll
                for (int j = 0; j < 4; ++j) {
                    int ljh = j * 16 + (lane & 15);
                    #pragma unroll
                    for (int i = 0; i < 4; ++i) {
                        int li = wm * 64 + i * 16 + (lane >> 4) * 4;
                        f32x4 vv;
                        #pragma unroll
                        for (int r = 0; r < 4; ++r)
                            vv[r] = fmaxf(acc[i][j][r] * scv[j] + shv[j], 0.f);
                        *(f32x4*)&epi[ljh][li] = vv;
                    }
                }
            }
            __syncthreads();
            #pragma unroll
            for (int q = 0; q < 8; ++q) {
                int idx = q * 256 + tid;
                int ch = idx >> 5, chunk = idx & 31;
                f32x4 v = *(const f32x4*)&epi[ch][chunk * 4];
                size_t base = ((size_t)(n * 512 + j0 + h * 64 + ch) << 14) + mb + chunk * 4;
                op[base] = v[0]; op[base + 1] = v[1]; op[base + 2] = v[2]; op[base + 3] = v[3];
            }
        }
    }
}

// ---------------- fused attention: sim (MFMA) + softmax (in-reg) + ctx (MFMA) ----------------
// 2-deep register prefetch on q2/KT staging.
__global__ __launch_bounds__(256) void attn_fused(
    const unsigned short* __restrict__ q2,   // [131072][512] fp16
    const unsigned short* __restrict__ ktg,  // [8][128][512] fp16 (rows>=19 zero)
    const unsigned short* __restrict__ vtg,  // [8][512][128] fp16 (cols>=19 zero)
    unsigned short* __restrict__ ctx)        // [131072][512] fp16 (aliases q2; per-block rows)
{
    __shared__ __align__(16) char lds[47104];
    unsigned short* stage = (unsigned short*)lds;
    unsigned short* vt_l  = (unsigned short*)lds;
    unsigned short* att_l = (unsigned short*)(lds + 36864);

    const int tid  = threadIdx.x;
    const int lane = tid & 63;
    const int w    = tid >> 6;
    const int i0   = blockIdx.x * 128;
    const int n    = blockIdx.x >> 7;
    const unsigned short* KT = ktg + n * 65536;
    const unsigned short* VT = vtg + n * 65536;

    size_t gA[4]; int loA[4];
    #pragma unroll
    for (int q = 0; q < 4; ++q) {
        int ca = q * 256 + tid;
        int r = ca >> 3, p = ca & 7;
        gA[q] = (size_t)(i0 + r) * 512 + p * 8;
        loA[q] = r * 64 + ((p ^ (r & 7)) << 3);
    }
    const int rB = tid >> 3, pB = tid & 7;
    const size_t gB = (size_t)rB * 512 + pB * 8;
    const int loB = 8192 + rB * 64 + ((pB ^ (rB & 7)) << 3);

    us8 vaA[4], vaB[4], vkA, vkB;
    #pragma unroll
    for (int q = 0; q < 4; ++q) {
        vaA[q] = *(const us8*)(q2 + gA[q]);
        vaB[q] = *(const us8*)(q2 + gA[q] + 64);
    }
    vkA = *(const us8*)(KT + gB);
    vkB = *(const us8*)(KT + gB + 64);

    f32x4 acc[2][2];
    #pragma unroll
    for (int i = 0; i < 2; ++i)
        #pragma unroll
        for (int j = 0; j < 2; ++j) acc[i][j] = (f32x4){0.f, 0.f, 0.f, 0.f};

    const int kch = lane >> 4;

#define ATTN_MFMA \
        _Pragma("unroll") \
        for (int s = 0; s < 2; ++s) { \
            half8 af[2], bf[2]; \
            _Pragma("unroll") \
            for (int i = 0; i < 2; ++i) { \
                int ra = w * 32 + i * 16 + (lane & 15); \
                af[i] = *(const half8*)(stage + ra * 64 + (((s * 4 + kch) ^ (ra & 7)) << 3)); \
            } \
            _Pragma("unroll") \
            for (int t = 0; t < 2; ++t) { \
                int rb = t * 16 + (lane & 15); \
                bf[t] = *(const half8*)(stage + 8192 + rb * 64 + (((s * 4 + kch) ^ (rb & 7)) << 3)); \
            } \
            _Pragma("unroll") \
            for (int i = 0; i < 2; ++i) \
                _Pragma("unroll") \
                for (int j = 0; j < 2; ++j) \
                    acc[i][j] = __builtin_amdgcn_mfma_f32_16x16x32_f16(af[i], bf[j], acc[i][j], 0, 0, 0); \
        }

    #pragma unroll
    for (int kk = 0; kk < 8; kk += 2) {
        __syncthreads();
        #pragma unroll
        for (int q = 0; q < 4; ++q) *(us8*)(stage + loA[q]) = vaA[q];
        *(us8*)(stage + loB) = vkA;
        __syncthreads();
        if (kk < 6) {
            #pragma unroll
            for (int q = 0; q < 4; ++q) vaA[q] = *(const us8*)(q2 + gA[q] + (kk + 2) * 64);
            vkA = *(const us8*)(KT + gB + (kk + 2) * 64);
        }
        ATTN_MFMA
        __syncthreads();
        #pragma unroll
        for (int q = 0; q < 4; ++q) *(us8*)(stage + loA[q]) = vaB[q];
        *(us8*)(stage + loB) = vkB;
        __syncthreads();
        if (kk < 5) {
            #pragma unroll
            for (int q = 0; q < 4; ++q) vaB[q] = *(const us8*)(q2 + gA[q] + (kk + 3) * 64);
            vkB = *(const us8*)(KT + gB + (kk + 3) * 64);
        }
        ATTN_MFMA
    }

    const float scale = 0.044194173824159216f;   // 512^-0.5
    const bool v1 = (lane & 15) < 3;
    unsigned short a16[2][4][2];
    #pragma unroll
    for (int i = 0; i < 2; ++i) {
        #pragma unroll
        for (int r = 0; r < 4; ++r) {
            float s0 = acc[i][0][r] * scale;
            float s1v = acc[i][1][r] * scale;
            float m = v1 ? fmaxf(s0, s1v) : s0;
            m = fmaxf(m, __shfl_xor(m, 1));
            m = fmaxf(m, __shfl_xor(m, 2));
            m = fmaxf(m, __shfl_xor(m, 4));
            m = fmaxf(m, __shfl_xor(m, 8));
            float a0 = __expf(s0 - m);
            float a1 = v1 ? __expf(s1v - m) : 0.f;
            float sm = a0 + a1;
            sm += __shfl_xor(sm, 1);
            sm += __shfl_xor(sm, 2);
            sm += __shfl_xor(sm, 4);
            sm += __shfl_xor(sm, 8);
            float inv = 1.0f / sm;
            a16[i][r][0] = f2h(a0 * inv);
            a16[i][r][1] = f2h(a1 * inv);
        }
    }
    #pragma unroll
    for (int i = 0; i < 2; ++i)
        #pragma unroll
        for (int r = 0; r < 4; ++r) {
            int R = w * 32 + i * 16 + (lane >> 4) * 4 + r;
            att_l[R * 40 + (lane & 15)]      = a16[i][r][0];
            att_l[R * 40 + 16 + (lane & 15)] = a16[i][r][1];
        }
    __syncthreads();

    #pragma unroll
    for (int q = 0; q < 8; ++q) {
        int id = q * 256 + tid;
        int c = id >> 2, part = id & 3;
        us8 v = *(const us8*)(VT + (size_t)c * 128 + part * 8);
        *(us4*)(vt_l + c * 36 + part * 8)     = (us4){v[0], v[1], v[2], v[3]};
        *(us4*)(vt_l + c * 36 + part * 8 + 4) = (us4){v[4], v[5], v[6], v[7]};
    }
    __syncthreads();

    half8 a2[2];
    #pragma unroll
    for (int i = 0; i < 2; ++i) {
        int R = w * 32 + i * 16 + (lane & 15);
        a2[i] = *(const half8*)(att_l + R * 40 + (lane >> 4) * 8);
    }
    #pragma unroll
    for (int jc = 0; jc < 4; ++jc) {
        half8 bf[8];
        #pragma unroll
        for (int t = 0; t < 8; ++t) {
            int c = jc * 128 + t * 16 + (lane & 15);
            const unsigned short* pb = vt_l + c * 36 + (lane >> 4) * 8;
            us4 lo = *(const us4*)(pb);
            us4 hi = *(const us4*)(pb + 4);
            us8 u = {lo[0], lo[1], lo[2], lo[3], hi[0], hi[1], hi[2], hi[3]};
            bf[t] = *(half8*)&u;
        }
        #pragma unroll
        for (int i = 0; i < 2; ++i) {
            #pragma unroll
            for (int t = 0; t < 8; ++t) {
                f32x4 o = __builtin_amdgcn_mfma_f32_16x16x32_f16(
                    a2[i], bf[t], (f32x4){0.f, 0.f, 0.f, 0.f}, 0, 0, 0);
                int col = jc * 128 + t * 16 + (lane & 15);
                int row = i0 + w * 32 + i * 16 + (lane >> 4) * 4;
                #pragma unroll
                for (int r = 0; r < 4; ++r)
                    ctx[(size_t)(row + r) * 512 + col] = f2h(o[r]);
            }
        }
    }
}

extern "C" void kernel_launch(void* const* d_in, const int* in_sizes, int n_in,
                              void* d_out, int out_size, void* d_ws, size_t ws_size,
                              hipStream_t stream)
{
    const float* x     = (const float*)d_in[0];
    const float* proxy = (const float*)d_in[1];
    const float* wp1   = (const float*)d_in[2];
    const float* wp2   = (const float*)d_in[3];
    const float* wo1   = (const float*)d_in[4];
    const float* wo2   = (const float*)d_in[5];
    const float* wd    = (const float*)d_in[6];
    const float* wu    = (const float*)d_in[7];
    const float* gp1 = (const float*)d_in[8],  *bp1 = (const float*)d_in[9];
    const float* mp1 = (const float*)d_in[10], *vp1 = (const float*)d_in[11];
    const float* gp2 = (const float*)d_in[12], *bp2 = (const float*)d_in[13];
    const float* mp2 = (const float*)d_in[14], *vp2 = (const float*)d_in[15];
    const float* go1 = (const float*)d_in[16], *bo1 = (const float*)d_in[17];
    const float* mo1 = (const float*)d_in[18], *vo1 = (const float*)d_in[19];
    const float* go2 = (const float*)d_in[20], *bo2 = (const float*)d_in[21];
    const float* mo2 = (const float*)d_in[22], *vo2 = (const float*)d_in[23];
    const float* gd  = (const float*)d_in[24], *bd  = (const float*)d_in[25];
    const float* md  = (const float*)d_in[26], *vd  = (const float*)d_in[27];
    const float* gu  = (const float*)d_in[28], *bu  = (const float*)d_in[29];
    const float* mu  = (const float*)d_in[30], *vu  = (const float*)d_in[31];

    char* ws = (char*)d_ws;
    unsigned short* r0   = (unsigned short*)ws;               // 134 MB: xT -> q2T -> ctxT (fp16)
    unsigned short* wp1h = (unsigned short*)(ws + 134217728);
    unsigned short* wp2h = wp1h + 262144;
    unsigned short* wuh  = wp2h + 262144;
    float* t1   = (float*)(wuh + 262144);
    float* kbuf = t1 + 8 * CH * KR;
    float* vbuf = kbuf + 8 * CH * KR;
    float* cons = vbuf + 8 * CH * KR;

    float* outf = (float*)d_out;                              // 268 MB fp32 output
    unsigned short* outh = (unsigned short*)d_out;
    unsigned short* q1T = outh;                               // [0, 67108864) fp16
    unsigned short* ktb = outh + 117440512;                   // fp16 [8][128][512]
    unsigned short* vtb = outh + 117964800;                   // fp16 [8][512][128]

    prep_kernel<<<1024, 256, 0, stream>>>(wp1, wp2, wu, wp1h, wp2h, wuh,
        gp1, bp1, mp1, vp1, gp2, bp2, mp2, vp2, gu, bu, mu, vu, cons);
    transpose_kernel<<<dim3(128, 8, 8), 256, 0, stream>>>(x, r0);
    kv1_kernel<<<dim3(8, 8), 256, 0, stream>>>(proxy, wo1, wd,
        go1, bo1, mo1, vo1, gd, bd, md, vd, t1, vbuf);
    kv2_kernel<<<dim3(8, 8), 256, 0, stream>>>(t1, wo2, go2, bo2, mo2, vo2, kbuf);
    pad_kernel<<<2048, 256, 0, stream>>>(kbuf, vbuf, ktb, vtb);

    // q1T = bn_relu(xT wp1^T) -> d_out low half
    gemm_nt<0, 1><<<4096, 256, 0, stream>>>(r0, wp1h, cons, cons + 512, q1T);
    // q2T = bn_relu(q1T wp2^T) -> r0
    gemm_nt<0, 1><<<4096, 256, 0, stream>>>(q1T, wp2h, cons + 1024, cons + 1536, r0);
    // fused attention: r0 (q2T) -> r0 (ctx), per-block row ownership
    attn_fused<<<1024, 256, 0, stream>>>(r0, ktb, vtb, r0);
    // out = bn_relu(wu ctx) -> d_out fp32 NCHW (overwrites all scratch last)
    gemm_nt<1, 1><<<4096, 256, 0, stream>>>(r0, wuh, cons + 2048, cons + 2560, outf);
}